// Round 2
// baseline (343.936 us; speedup 1.0000x reference)
//
#include <hip/hip_runtime.h>
#include <stdint.h>

// LocalAttention: x[2,2048,1024] -> QKV proj -> anti-local attention (keep |i-j|>16) -> out proj.
// Round 1 resubmit (round-1 bench died on UnresponsiveContainer infra error).
// ws layout (u16 elements): xb[4M] (reused as attn-out), wq/wk/wv/wo[1M each], q[4M], k[4M], vT[4M] = 40MB.

typedef unsigned short u16;
typedef short bf16x8 __attribute__((ext_vector_type(8)));
typedef float f32x4 __attribute__((ext_vector_type(4)));

#define MFMA16 __builtin_amdgcn_mfma_f32_16x16x32_bf16

__device__ __forceinline__ u16 f2bf(float f) {
  union { float f; uint32_t u; } v; v.f = f;
  return (u16)((v.u + 0x7fffu + ((v.u >> 16) & 1u)) >> 16);
}

__device__ __forceinline__ void gload_lds16(const void* g, void* l) {
  __builtin_amdgcn_global_load_lds(
      (const __attribute__((address_space(1))) unsigned int*)g,
      (__attribute__((address_space(3))) unsigned int*)l, 16, 0, 0);
}

// ---------------- fp32 -> bf16 conversion ----------------
__global__ void f2b_kernel(const float* __restrict__ in, u16* __restrict__ out, int n4) {
  int i = blockIdx.x * blockDim.x + threadIdx.x;
  if (i < n4) {
    float4 v = reinterpret_cast<const float4*>(in)[i];
    ushort4 o;
    o.x = f2bf(v.x); o.y = f2bf(v.y); o.z = f2bf(v.z); o.w = f2bf(v.w);
    reinterpret_cast<ushort4*>(out)[i] = o;
  }
}

// ---------------- GEMM: C[M=4096,N=1024] = A[M,K=1024] @ W[N,K]^T + bias ----------------
// MODE 0: out bf16 [B,H,T,D] (qkv head layout), scaled
// MODE 1: out bf16 [B,H,D,T] (V transposed)
// MODE 2: out fp32 flat [M,N]
template<int MODE>
__global__ __launch_bounds__(256) void gemm_bt(
    const u16* __restrict__ A, const u16* __restrict__ Bw,
    const float* __restrict__ bias, void* __restrict__ outp, float scale)
{
  constexpr int K = 1024;
  __shared__ __align__(16) u16 As[128 * 64];
  __shared__ __align__(16) u16 Bs[128 * 64];
  const int t = threadIdx.x;
  const int lane = t & 63;
  const int wv = t >> 6;
  const int bm0 = blockIdx.x * 128;
  const int bn0 = blockIdx.y * 128;
  const int wm = (wv >> 1) * 64;
  const int wn = (wv & 1) * 64;
  const int lg = lane >> 4;   // 0..3
  const int lr = lane & 15;   // 0..15

  f32x4 acc[4][4];
  for (int i = 0; i < 4; ++i)
    for (int j = 0; j < 4; ++j) acc[i][j] = (f32x4)0.0f;

  for (int k0 = 0; k0 < K; k0 += 64) {
    for (int it = 0; it < 4; ++it) {
      int chunk = it * 256 + t;          // per-lane 16B chunk id (0..1023)
      int row = chunk >> 3;              // /8 chunks per 64-elem row
      int col = (chunk & 7) * 8;
      int base = (it * 256 + wv * 64) * 8;  // wave-uniform LDS elem base
      gload_lds16(A  + (size_t)(bm0 + row) * K + k0 + col, &As[base]);
      gload_lds16(Bw + (size_t)(bn0 + row) * K + k0 + col, &Bs[base]);
    }
    __syncthreads();
    for (int kk = 0; kk < 2; ++kk) {
      bf16x8 af[4], bfr[4];
      for (int i = 0; i < 4; ++i)
        af[i] = *reinterpret_cast<const bf16x8*>(&As[(wm + i * 16 + lr) * 64 + kk * 32 + lg * 8]);
      for (int j = 0; j < 4; ++j)
        bfr[j] = *reinterpret_cast<const bf16x8*>(&Bs[(wn + j * 16 + lr) * 64 + kk * 32 + lg * 8]);
      for (int i = 0; i < 4; ++i)
        for (int j = 0; j < 4; ++j)
          acc[i][j] = MFMA16(af[i], bfr[j], acc[i][j], 0, 0, 0);
    }
    __syncthreads();
  }

  for (int j = 0; j < 4; ++j) {
    int gn = bn0 + wn + j * 16 + lr;
    float bv = bias[gn];
    for (int i = 0; i < 4; ++i) {
      for (int r = 0; r < 4; ++r) {
        int gm = bm0 + wm + i * 16 + lg * 4 + r;
        float val = (acc[i][j][r] + bv) * scale;
        if (MODE == 2) {
          ((float*)outp)[(size_t)gm * 1024 + gn] = val;
        } else {
          int b = gm >> 11, tt = gm & 2047;
          int h = gn >> 6,  d = gn & 63;
          u16 o = f2bf(val);
          if (MODE == 0)
            ((u16*)outp)[((size_t)(b * 16 + h) * 2048 + tt) * 64 + d] = o;
          else
            ((u16*)outp)[((size_t)(b * 16 + h) * 64 + d) * 2048 + tt] = o;
        }
      }
    }
  }
}

// ---------------- attention ----------------
// grid (T/64, B*H), block 256 (4 waves). Wave w owns q-rows [q0, q0+16).
// q: [B,H,T,D] bf16 (pre-scaled by 1/8), k: [B,H,T,D] bf16, vT: [B,H,D,T] bf16.
// out ab: [B,T,C] bf16. Mask: attend iff |i-j| > 16.
__global__ __launch_bounds__(256) void attn_kernel(
    const u16* __restrict__ qb, const u16* __restrict__ kb,
    const u16* __restrict__ vtb, u16* __restrict__ ab)
{
  __shared__ __align__(16) u16 P[4][16 * 32];
  const int t = threadIdx.x;
  const int lane = t & 63;
  const int wv = t >> 6;
  const int lg = lane >> 4, lr = lane & 15;
  const int bh = blockIdx.y;                 // b*16+h
  const int q0 = blockIdx.x * 64 + wv * 16;

  const u16* Qp = qb + (size_t)bh * 2048 * 64;
  const u16* Kp = kb + (size_t)bh * 2048 * 64;
  const u16* Vt = vtb + (size_t)bh * 64 * 2048;

  bf16x8 qf[2];
  for (int kk = 0; kk < 2; ++kk)
    qf[kk] = *reinterpret_cast<const bf16x8*>(&Qp[(size_t)(q0 + lr) * 64 + kk * 32 + lg * 8]);

  f32x4 o[4];
  for (int d = 0; d < 4; ++d) o[d] = (f32x4)0.0f;
  float mrow[4], lrow[4];
  for (int r = 0; r < 4; ++r) { mrow[r] = -1e30f; lrow[r] = 0.0f; }

  for (int j0 = 0; j0 < 2048; j0 += 32) {
    // S = Q K^T  (scale folded into Q)
    f32x4 s[2];
    for (int kc = 0; kc < 2; ++kc) {
      bf16x8 kf0 = *reinterpret_cast<const bf16x8*>(&Kp[(size_t)(j0 + kc * 16 + lr) * 64 + lg * 8]);
      bf16x8 kf1 = *reinterpret_cast<const bf16x8*>(&Kp[(size_t)(j0 + kc * 16 + lr) * 64 + 32 + lg * 8]);
      f32x4 z = (f32x4)0.0f;
      z = MFMA16(qf[0], kf0, z, 0, 0, 0);
      z = MFMA16(qf[1], kf1, z, 0, 0, 0);
      s[kc] = z;
    }
    // mask band |i-j| <= 16 (only chunks overlapping the band)
    if (j0 + 31 >= q0 - 16 && j0 <= q0 + 31) {
      for (int kc = 0; kc < 2; ++kc)
        for (int r = 0; r < 4; ++r) {
          int i = q0 + lg * 4 + r;
          int j = j0 + kc * 16 + lr;
          int dd = i - j; if (dd < 0) dd = -dd;
          if (dd <= 16) s[kc][r] = -1e38f;
        }
    }
    // online softmax (rows live across the 16 lanes of each lg-group)
    float alpha[4], p0[4], p1[4];
    for (int r = 0; r < 4; ++r) {
      float rm = fmaxf(s[0][r], s[1][r]);
      rm = fmaxf(rm, __shfl_xor(rm, 1));
      rm = fmaxf(rm, __shfl_xor(rm, 2));
      rm = fmaxf(rm, __shfl_xor(rm, 4));
      rm = fmaxf(rm, __shfl_xor(rm, 8));
      float mnew = fmaxf(mrow[r], rm);
      alpha[r] = __expf(mrow[r] - mnew);
      p0[r] = __expf(s[0][r] - mnew);
      p1[r] = __expf(s[1][r] - mnew);
      float rs = p0[r] + p1[r];
      rs += __shfl_xor(rs, 1);
      rs += __shfl_xor(rs, 2);
      rs += __shfl_xor(rs, 4);
      rs += __shfl_xor(rs, 8);
      lrow[r] = lrow[r] * alpha[r] + rs;
      mrow[r] = mnew;
    }
    for (int d = 0; d < 4; ++d)
      for (int r = 0; r < 4; ++r) o[d][r] *= alpha[r];
    // P -> LDS (S layout) then reload in MFMA-A layout
    for (int r = 0; r < 4; ++r) {
      P[wv][(lg * 4 + r) * 32 + lr]      = f2bf(p0[r]);
      P[wv][(lg * 4 + r) * 32 + 16 + lr] = f2bf(p1[r]);
    }
    asm volatile("s_waitcnt lgkmcnt(0)" ::: "memory");
    bf16x8 pa = *reinterpret_cast<const bf16x8*>(&P[wv][lr * 32 + lg * 8]);
    for (int d = 0; d < 4; ++d) {
      bf16x8 vf = *reinterpret_cast<const bf16x8*>(&Vt[(size_t)(d * 16 + lr) * 2048 + j0 + lg * 8]);
      o[d] = MFMA16(pa, vf, o[d], 0, 0, 0);
    }
  }

  int b = bh >> 4, h = bh & 15;
  for (int d = 0; d < 4; ++d)
    for (int r = 0; r < 4; ++r) {
      float val = o[d][r] / lrow[r];
      ab[((size_t)b * 2048 + q0 + lg * 4 + r) * 1024 + h * 64 + d * 16 + lr] = f2bf(val);
    }
}

// ---------------- launcher ----------------
extern "C" void kernel_launch(void* const* d_in, const int* in_sizes, int n_in,
                              void* d_out, int out_size, void* d_ws, size_t ws_size,
                              hipStream_t stream) {
  const float* x  = (const float*)d_in[0];
  const float* Wq = (const float*)d_in[1];
  const float* bq = (const float*)d_in[2];
  const float* Wk = (const float*)d_in[3];
  const float* bk = (const float*)d_in[4];
  const float* Wv = (const float*)d_in[5];
  const float* bv = (const float*)d_in[6];
  const float* Wo = (const float*)d_in[7];
  const float* bo = (const float*)d_in[8];

  u16* ws  = (u16*)d_ws;
  u16* xb  = ws;                 // 4096*1024 bf16 (reused for attention output)
  u16* wqb = ws + 4194304;
  u16* wkb = ws + 5242880;
  u16* wvb = ws + 6291456;
  u16* wob = ws + 7340032;
  u16* qbf = ws + 8388608;
  u16* kbf = ws + 12582912;
  u16* vbf = ws + 16777216;
  u16* ab  = xb;

  // fp32 -> bf16
  f2b_kernel<<<4096, 256, 0, stream>>>(x,  xb,  1048576);
  f2b_kernel<<<1024, 256, 0, stream>>>(Wq, wqb, 262144);
  f2b_kernel<<<1024, 256, 0, stream>>>(Wk, wkb, 262144);
  f2b_kernel<<<1024, 256, 0, stream>>>(Wv, wvb, 262144);
  f2b_kernel<<<1024, 256, 0, stream>>>(Wo, wob, 262144);

  dim3 gg(32, 8);
  gemm_bt<0><<<gg, 256, 0, stream>>>(xb, wqb, bq, qbf, 0.125f);  // Q (scaled)
  gemm_bt<0><<<gg, 256, 0, stream>>>(xb, wkb, bk, kbf, 1.0f);    // K
  gemm_bt<1><<<gg, 256, 0, stream>>>(xb, wvb, bv, vbf, 1.0f);    // V^T

  attn_kernel<<<dim3(32, 32), 256, 0, stream>>>(qbf, kbf, vbf, ab);

  gemm_bt<2><<<gg, 256, 0, stream>>>(ab, wob, bo, d_out, 1.0f);  // out proj (fp32)
}

// Round 5
// 264.372 us; speedup vs baseline: 1.3010x; 1.3010x over previous
//
#include <hip/hip_runtime.h>
#include <stdint.h>

// LocalAttention: x[2,2048,1024] -> QKV proj -> anti-local attention (keep |i-j|>16) -> out proj.
// Round 4 resubmit (rounds 3+4 died on UnresponsiveContainer infra errors; same container).
// Swapped-operand attention (q-row lane-local softmax), KVBLK=64, 32 q-rows/wave,
// cvt_pk bf16 packing, XOR-swizzled P LDS, defer-max rescale.

typedef unsigned short u16;
typedef short bf16x8 __attribute__((ext_vector_type(8)));
typedef float f32x4 __attribute__((ext_vector_type(4)));

#define MFMA16 __builtin_amdgcn_mfma_f32_16x16x32_bf16

__device__ __forceinline__ u16 f2bf(float f) {
  union { float f; uint32_t u; } v; v.f = f;
  return (u16)((v.u + 0x7fffu + ((v.u >> 16) & 1u)) >> 16);
}

__device__ __forceinline__ uint32_t cvt_pk_bf16(float lo, float hi) {
  uint32_t d;
  asm("v_cvt_pk_bf16_f32 %0, %1, %2" : "=v"(d) : "v"(lo), "v"(hi));
  return d;
}

__device__ __forceinline__ void gload_lds16(const void* g, void* l) {
  __builtin_amdgcn_global_load_lds(
      (const __attribute__((address_space(1))) unsigned int*)g,
      (__attribute__((address_space(3))) unsigned int*)l, 16, 0, 0);
}

// ---------------- fp32 -> bf16 conversion ----------------
__global__ void f2b_kernel(const float* __restrict__ in, u16* __restrict__ out, int n4) {
  int i = blockIdx.x * blockDim.x + threadIdx.x;
  if (i < n4) {
    float4 v = reinterpret_cast<const float4*>(in)[i];
    ushort4 o;
    o.x = f2bf(v.x); o.y = f2bf(v.y); o.z = f2bf(v.z); o.w = f2bf(v.w);
    reinterpret_cast<ushort4*>(out)[i] = o;
  }
}

// all four weight matrices in one launch (grid.y selects)
__global__ void f2b4_kernel(const float* __restrict__ a, const float* __restrict__ b,
                            const float* __restrict__ c, const float* __restrict__ d,
                            u16* __restrict__ oa, u16* __restrict__ ob,
                            u16* __restrict__ oc, u16* __restrict__ od, int n4) {
  int i = blockIdx.x * blockDim.x + threadIdx.x;
  if (i >= n4) return;
  int w = blockIdx.y;
  const float* src = (w == 0) ? a : (w == 1) ? b : (w == 2) ? c : d;
  u16* dst = (w == 0) ? oa : (w == 1) ? ob : (w == 2) ? oc : od;
  float4 v = reinterpret_cast<const float4*>(src)[i];
  ushort4 o;
  o.x = f2bf(v.x); o.y = f2bf(v.y); o.z = f2bf(v.z); o.w = f2bf(v.w);
  reinterpret_cast<ushort4*>(dst)[i] = o;
}

// ---------------- GEMM: C[M=4096,N=1024] = A[M,K=1024] @ W[N,K]^T + bias ----------------
// MODE 0: out bf16 [B,H,T,D] (qkv head layout), scaled
// MODE 1: out bf16 [B,H,D,T] (V transposed)
// MODE 2: out fp32 flat [M,N]
template<int MODE>
__global__ __launch_bounds__(256) void gemm_bt(
    const u16* __restrict__ A, const u16* __restrict__ Bw,
    const float* __restrict__ bias, void* __restrict__ outp, float scale)
{
  constexpr int K = 1024;
  __shared__ __align__(16) u16 As[128 * 64];
  __shared__ __align__(16) u16 Bs[128 * 64];
  const int t = threadIdx.x;
  const int lane = t & 63;
  const int wv = t >> 6;
  const int bm0 = blockIdx.x * 128;
  const int bn0 = blockIdx.y * 128;
  const int wm = (wv >> 1) * 64;
  const int wn = (wv & 1) * 64;
  const int lg = lane >> 4;   // 0..3
  const int lr = lane & 15;   // 0..15

  f32x4 acc[4][4];
  for (int i = 0; i < 4; ++i)
    for (int j = 0; j < 4; ++j) acc[i][j] = (f32x4)0.0f;

  for (int k0 = 0; k0 < K; k0 += 64) {
    for (int it = 0; it < 4; ++it) {
      int chunk = it * 256 + t;          // per-lane 16B chunk id (0..1023)
      int row = chunk >> 3;              // /8 chunks per 64-elem row
      int col = (chunk & 7) * 8;
      int base = (it * 256 + wv * 64) * 8;  // wave-uniform LDS elem base
      gload_lds16(A  + (size_t)(bm0 + row) * K + k0 + col, &As[base]);
      gload_lds16(Bw + (size_t)(bn0 + row) * K + k0 + col, &Bs[base]);
    }
    __syncthreads();
    for (int kk = 0; kk < 2; ++kk) {
      bf16x8 af[4], bfr[4];
      for (int i = 0; i < 4; ++i)
        af[i] = *reinterpret_cast<const bf16x8*>(&As[(wm + i * 16 + lr) * 64 + kk * 32 + lg * 8]);
      for (int j = 0; j < 4; ++j)
        bfr[j] = *reinterpret_cast<const bf16x8*>(&Bs[(wn + j * 16 + lr) * 64 + kk * 32 + lg * 8]);
      for (int i = 0; i < 4; ++i)
        for (int j = 0; j < 4; ++j)
          acc[i][j] = MFMA16(af[i], bfr[j], acc[i][j], 0, 0, 0);
    }
    __syncthreads();
  }

  for (int j = 0; j < 4; ++j) {
    int gn = bn0 + wn + j * 16 + lr;
    float bv = bias[gn];
    for (int i = 0; i < 4; ++i) {
      for (int r = 0; r < 4; ++r) {
        int gm = bm0 + wm + i * 16 + lg * 4 + r;
        float val = (acc[i][j][r] + bv) * scale;
        if (MODE == 2) {
          ((float*)outp)[(size_t)gm * 1024 + gn] = val;
        } else {
          int b = gm >> 11, tt = gm & 2047;
          int h = gn >> 6,  d = gn & 63;
          u16 o = f2bf(val);
          if (MODE == 0)
            ((u16*)outp)[((size_t)(b * 16 + h) * 2048 + tt) * 64 + d] = o;
          else
            ((u16*)outp)[((size_t)(b * 16 + h) * 64 + d) * 2048 + tt] = o;
        }
      }
    }
  }
}

// ---------------- attention (swapped operands) ----------------
// grid (T/128, B*H), block 256 (4 waves). Wave w owns q-rows [bx*128 + w*32, +32).
// qkv: q [B,H,T,D] bf16 (pre-scaled by 1/8), k [B,H,T,D] bf16, vT [B,H,D,T] bf16.
// Swapped QK^T: s = mfma(Kfrag, Qfrag) -> lane holds q-row = lane&15, keys in regs.
// Swapped PV:   o = mfma(Vfrag, Pfrag) -> o cols = q-row = lane&15 (stats aligned, no shuffles).
__global__ __launch_bounds__(256, 2) void attn_kernel(
    const u16* __restrict__ qb, const u16* __restrict__ kb,
    const u16* __restrict__ vtb, u16* __restrict__ ab)
{
  __shared__ __align__(16) u16 Pl[4][32 * 64];  // per-wave P tile, XOR-swizzled rows of 128B
  const int t = threadIdx.x;
  const int lane = t & 63;
  const int wv = t >> 6;
  const int lg = lane >> 4, lr = lane & 15;
  const int bh = blockIdx.y;                 // b*16+h
  const int q0 = blockIdx.x * 128 + wv * 32;

  const u16* Qp = qb + (size_t)bh * 2048 * 64;
  const u16* Kp = kb + (size_t)bh * 2048 * 64;
  const u16* Vt = vtb + (size_t)bh * 64 * 2048;
  char* Pw = (char*)&Pl[wv][0];
  const int swz = (lr & 7) << 4;             // row-determined XOR swizzle (row&7 == lr&7)

  // Q fragments: qf[qi][h] = Q[q0+qi*16+lr][h*32 + lg*8 ..+7]
  bf16x8 qf[2][2];
  for (int qi = 0; qi < 2; ++qi)
    for (int h = 0; h < 2; ++h)
      qf[qi][h] = *reinterpret_cast<const bf16x8*>(&Qp[(size_t)(q0 + qi * 16 + lr) * 64 + h * 32 + lg * 8]);

  f32x4 o[2][4];                             // o[qi][d]: col=q(lr), row=d*16+lg*4+r
  for (int qi = 0; qi < 2; ++qi)
    for (int d = 0; d < 4; ++d) o[qi][d] = (f32x4)0.0f;
  float m[2] = {-1e30f, -1e30f};
  float l[2] = {0.0f, 0.0f};

  for (int j0 = 0; j0 < 2048; j0 += 64) {
    // ---- QK^T (swapped): s[qi][kc] -> lane: q=q0+qi*16+lr, key=j0+kc*16+lg*4+r
    f32x4 s[2][4];
    for (int kc = 0; kc < 4; ++kc) {
      bf16x8 kf0 = *reinterpret_cast<const bf16x8*>(&Kp[(size_t)(j0 + kc * 16 + lr) * 64 + lg * 8]);
      bf16x8 kf1 = *reinterpret_cast<const bf16x8*>(&Kp[(size_t)(j0 + kc * 16 + lr) * 64 + 32 + lg * 8]);
      for (int qi = 0; qi < 2; ++qi) {
        f32x4 z = (f32x4)0.0f;
        z = MFMA16(kf0, qf[qi][0], z, 0, 0, 0);
        z = MFMA16(kf1, qf[qi][1], z, 0, 0, 0);
        s[qi][kc] = z;
      }
    }
    // ---- mask band |i-j| <= 16 (only chunks overlapping this wave's band)
    if (j0 + 63 >= q0 - 16 && j0 <= q0 + 47) {
      for (int qi = 0; qi < 2; ++qi)
        for (int kc = 0; kc < 4; ++kc)
          for (int r = 0; r < 4; ++r) {
            int i = q0 + qi * 16 + lr;
            int j = j0 + kc * 16 + lg * 4 + r;
            int dd = i - j; if (dd < 0) dd = -dd;
            if (dd <= 16) s[qi][kc][r] = -1e38f;
          }
    }
    // ---- chunk row-max (register tree + 2 shuffles)
    float pm[2];
    for (int qi = 0; qi < 2; ++qi) {
      f32x4 t4 = s[qi][0];
      t4 = __builtin_elementwise_max(t4, s[qi][1]);
      t4 = __builtin_elementwise_max(t4, s[qi][2]);
      t4 = __builtin_elementwise_max(t4, s[qi][3]);
      float x = fmaxf(fmaxf(t4[0], t4[1]), fmaxf(t4[2], t4[3]));
      x = fmaxf(x, __shfl_xor(x, 16));
      x = fmaxf(x, __shfl_xor(x, 32));
      pm[qi] = x;
    }
    // ---- defer-max: rescale only when max grew past threshold
    bool need = (pm[0] > m[0] + 8.0f) || (pm[1] > m[1] + 8.0f);
    if (__any((int)need)) {
      for (int qi = 0; qi < 2; ++qi) {
        float mn = fmaxf(m[qi], pm[qi]);
        float a = __expf(m[qi] - mn);
        m[qi] = mn;
        l[qi] *= a;
        for (int d = 0; d < 4; ++d) o[qi][d] *= a;
      }
    }
    // ---- p = exp(s-m), pack to LDS, accumulate l
    for (int qi = 0; qi < 2; ++qi) {
      float sum = 0.0f;
      int rowbase = (qi * 16 + lr) * 128;
      for (int kc = 0; kc < 4; ++kc) {
        float p0 = __expf(s[qi][kc][0] - m[qi]);
        float p1 = __expf(s[qi][kc][1] - m[qi]);
        float p2 = __expf(s[qi][kc][2] - m[qi]);
        float p3 = __expf(s[qi][kc][3] - m[qi]);
        sum += (p0 + p1) + (p2 + p3);
        uint2 pk;
        pk.x = cvt_pk_bf16(p0, p1);
        pk.y = cvt_pk_bf16(p2, p3);
        *reinterpret_cast<uint2*>(Pw + ((rowbase + kc * 32 + lg * 8) ^ swz)) = pk;
      }
      sum += __shfl_xor(sum, 16);
      sum += __shfl_xor(sum, 32);
      l[qi] += sum;
    }
    asm volatile("s_waitcnt lgkmcnt(0)" ::: "memory");
    // ---- PV (swapped): o[qi][d] += mfma(Vfrag, Pfrag)
    for (int kh = 0; kh < 2; ++kh) {
      bf16x8 pa[2];
      for (int qi = 0; qi < 2; ++qi)
        pa[qi] = *reinterpret_cast<const bf16x8*>(
            Pw + (((qi * 16 + lr) * 128 + kh * 64 + lg * 16) ^ swz));
      for (int d = 0; d < 4; ++d) {
        bf16x8 vf = *reinterpret_cast<const bf16x8*>(
            &Vt[(size_t)(d * 16 + lr) * 2048 + j0 + kh * 32 + lg * 8]);
        for (int qi = 0; qi < 2; ++qi)
          o[qi][d] = MFMA16(vf, pa[qi], o[qi][d], 0, 0, 0);
      }
    }
  }

  // ---- epilogue: normalize and write [B,T,C] bf16
  int b = bh >> 4, h = bh & 15;
  for (int qi = 0; qi < 2; ++qi) {
    float inv = 1.0f / l[qi];
    size_t rowoff = ((size_t)b * 2048 + q0 + qi * 16 + lr) * 1024 + h * 64;
    for (int d = 0; d < 4; ++d) {
      uint2 pk;
      pk.x = cvt_pk_bf16(o[qi][d][0] * inv, o[qi][d][1] * inv);
      pk.y = cvt_pk_bf16(o[qi][d][2] * inv, o[qi][d][3] * inv);
      *reinterpret_cast<uint2*>(&ab[rowoff + d * 16 + lg * 4]) = pk;
    }
  }
}

// ---------------- launcher ----------------
extern "C" void kernel_launch(void* const* d_in, const int* in_sizes, int n_in,
                              void* d_out, int out_size, void* d_ws, size_t ws_size,
                              hipStream_t stream) {
  const float* x  = (const float*)d_in[0];
  const float* Wq = (const float*)d_in[1];
  const float* bq = (const float*)d_in[2];
  const float* Wk = (const float*)d_in[3];
  const float* bk = (const float*)d_in[4];
  const float* Wv = (const float*)d_in[5];
  const float* bv = (const float*)d_in[6];
  const float* Wo = (const float*)d_in[7];
  const float* bo = (const float*)d_in[8];

  u16* ws  = (u16*)d_ws;
  u16* xb  = ws;                 // 4096*1024 bf16 (reused for attention output)
  u16* wqb = ws + 4194304;
  u16* wkb = ws + 5242880;
  u16* wvb = ws + 6291456;
  u16* wob = ws + 7340032;
  u16* qbf = ws + 8388608;
  u16* kbf = ws + 12582912;
  u16* vbf = ws + 16777216;
  u16* ab  = xb;

  // fp32 -> bf16
  f2b_kernel<<<4096, 256, 0, stream>>>(x, xb, 1048576);
  f2b4_kernel<<<dim3(1024, 4), 256, 0, stream>>>(Wq, Wk, Wv, Wo, wqb, wkb, wvb, wob, 262144);

  dim3 gg(32, 8);
  gemm_bt<0><<<gg, 256, 0, stream>>>(xb, wqb, bq, qbf, 0.125f);  // Q (scaled)
  gemm_bt<0><<<gg, 256, 0, stream>>>(xb, wkb, bk, kbf, 1.0f);    // K
  gemm_bt<1><<<gg, 256, 0, stream>>>(xb, wvb, bv, vbf, 1.0f);    // V^T

  attn_kernel<<<dim3(16, 32), 256, 0, stream>>>(qbf, kbf, vbf, ab);

  gemm_bt<2><<<gg, 256, 0, stream>>>(ab, wob, bo, d_out, 1.0f);  // out proj (fp32)
}

// Round 8
// 178.727 us; speedup vs baseline: 1.9244x; 1.4792x over previous
//
#include <hip/hip_runtime.h>
#include <stdint.h>

// LocalAttention: x[2,2048,1024] -> QKV proj -> anti-local attention (keep |i-j|>16) -> out proj.
// Round 8: bisection round. Round-5 attention (PASSED) + linear gload_lds K/V double-buffer
// (no K/V swizzle anywhere) + XCD remap. Isolates r6/r7's NaN to the swizzled-read path vs structure.

typedef unsigned short u16;
typedef short bf16x8 __attribute__((ext_vector_type(8)));
typedef float f32x4 __attribute__((ext_vector_type(4)));

#define MFMA16 __builtin_amdgcn_mfma_f32_16x16x32_bf16

__device__ __forceinline__ u16 f2bf(float f) {
  union { float f; uint32_t u; } v; v.f = f;
  return (u16)((v.u + 0x7fffu + ((v.u >> 16) & 1u)) >> 16);
}

__device__ __forceinline__ uint32_t cvt_pk_bf16(float lo, float hi) {
  uint32_t d;
  asm("v_cvt_pk_bf16_f32 %0, %1, %2" : "=v"(d) : "v"(lo), "v"(hi));
  return d;
}

__device__ __forceinline__ void gload_lds16(const void* g, void* l) {
  __builtin_amdgcn_global_load_lds(
      (const __attribute__((address_space(1))) unsigned int*)g,
      (__attribute__((address_space(3))) unsigned int*)l, 16, 0, 0);
}

// ---------------- fp32 -> bf16 conversion ----------------
__global__ void f2b_kernel(const float* __restrict__ in, u16* __restrict__ out, int n4) {
  int i = blockIdx.x * blockDim.x + threadIdx.x;
  if (i < n4) {
    float4 v = reinterpret_cast<const float4*>(in)[i];
    ushort4 o;
    o.x = f2bf(v.x); o.y = f2bf(v.y); o.z = f2bf(v.z); o.w = f2bf(v.w);
    reinterpret_cast<ushort4*>(out)[i] = o;
  }
}

// all four weight matrices in one launch (grid.y selects)
__global__ void f2b4_kernel(const float* __restrict__ a, const float* __restrict__ b,
                            const float* __restrict__ c, const float* __restrict__ d,
                            u16* __restrict__ oa, u16* __restrict__ ob,
                            u16* __restrict__ oc, u16* __restrict__ od, int n4) {
  int i = blockIdx.x * blockDim.x + threadIdx.x;
  if (i >= n4) return;
  int w = blockIdx.y;
  const float* src = (w == 0) ? a : (w == 1) ? b : (w == 2) ? c : d;
  u16* dst = (w == 0) ? oa : (w == 1) ? ob : (w == 2) ? oc : od;
  float4 v = reinterpret_cast<const float4*>(src)[i];
  ushort4 o;
  o.x = f2bf(v.x); o.y = f2bf(v.y); o.z = f2bf(v.z); o.w = f2bf(v.w);
  reinterpret_cast<ushort4*>(dst)[i] = o;
}

// ---------------- GEMM: C[M=4096,N=1024] = A[M,K=1024] @ W[N,K]^T + bias ----------------
// MODE 0: out bf16 [B,H,T,D] (qkv head layout), scaled
// MODE 1: out bf16 [B,H,D,T] (V transposed)
// MODE 2: out fp32 flat [M,N]
template<int MODE>
__global__ __launch_bounds__(256) void gemm_bt(
    const u16* __restrict__ A, const u16* __restrict__ Bw,
    const float* __restrict__ bias, void* __restrict__ outp, float scale)
{
  constexpr int K = 1024;
  __shared__ __align__(16) u16 As[128 * 64];
  __shared__ __align__(16) u16 Bs[128 * 64];
  const int t = threadIdx.x;
  const int lane = t & 63;
  const int wv = t >> 6;
  const int bm0 = blockIdx.x * 128;
  const int bn0 = blockIdx.y * 128;
  const int wm = (wv >> 1) * 64;
  const int wn = (wv & 1) * 64;
  const int lg = lane >> 4;   // 0..3
  const int lr = lane & 15;   // 0..15

  f32x4 acc[4][4];
  for (int i = 0; i < 4; ++i)
    for (int j = 0; j < 4; ++j) acc[i][j] = (f32x4)0.0f;

  for (int k0 = 0; k0 < K; k0 += 64) {
    for (int it = 0; it < 4; ++it) {
      int chunk = it * 256 + t;          // per-lane 16B chunk id (0..1023)
      int row = chunk >> 3;              // /8 chunks per 64-elem row
      int col = (chunk & 7) * 8;
      int base = (it * 256 + wv * 64) * 8;  // wave-uniform LDS elem base
      gload_lds16(A  + (size_t)(bm0 + row) * K + k0 + col, &As[base]);
      gload_lds16(Bw + (size_t)(bn0 + row) * K + k0 + col, &Bs[base]);
    }
    __syncthreads();
    for (int kk = 0; kk < 2; ++kk) {
      bf16x8 af[4], bfr[4];
      for (int i = 0; i < 4; ++i)
        af[i] = *reinterpret_cast<const bf16x8*>(&As[(wm + i * 16 + lr) * 64 + kk * 32 + lg * 8]);
      for (int j = 0; j < 4; ++j)
        bfr[j] = *reinterpret_cast<const bf16x8*>(&Bs[(wn + j * 16 + lr) * 64 + kk * 32 + lg * 8]);
      for (int i = 0; i < 4; ++i)
        for (int j = 0; j < 4; ++j)
          acc[i][j] = MFMA16(af[i], bfr[j], acc[i][j], 0, 0, 0);
    }
    __syncthreads();
  }

  for (int j = 0; j < 4; ++j) {
    int gn = bn0 + wn + j * 16 + lr;
    float bv = bias[gn];
    for (int i = 0; i < 4; ++i) {
      for (int r = 0; r < 4; ++r) {
        int gm = bm0 + wm + i * 16 + lg * 4 + r;
        float val = (acc[i][j][r] + bv) * scale;
        if (MODE == 2) {
          ((float*)outp)[(size_t)gm * 1024 + gn] = val;
        } else {
          int b = gm >> 11, tt = gm & 2047;
          int h = gn >> 6,  d = gn & 63;
          u16 o = f2bf(val);
          if (MODE == 0)
            ((u16*)outp)[((size_t)(b * 16 + h) * 2048 + tt) * 64 + d] = o;
          else
            ((u16*)outp)[((size_t)(b * 16 + h) * 64 + d) * 2048 + tt] = o;
        }
      }
    }
  }
}

// ---------------- attention (round-5 body + linear LDS K/V dbuf + XCD remap) ----------------
// grid 512 blocks remapped XCD-aware. Block: 4 waves, 128 q-rows; wave owns 32 q-rows.
// K tile [64 keys][64 d] and V tile [64 d][64 keys] staged LINEAR in LDS via gload_lds,
// double-buffered, one barrier per iteration. K/V LDS reads = round-5 global reads, redirected.
__global__ __launch_bounds__(256, 2) void attn_kernel(
    const u16* __restrict__ qb, const u16* __restrict__ kb,
    const u16* __restrict__ vtb, u16* __restrict__ ab)
{
  __shared__ __align__(16) u16 Kb[2][64 * 64];
  __shared__ __align__(16) u16 Vb[2][64 * 64];
  __shared__ __align__(16) u16 Pl[4][32 * 64];

  // XCD-aware remap: 512 = 8 XCDs x 64; XCD k serves heads 4k..4k+3 (2MB K/V -> L2-fits)
  const int bid = blockIdx.x + gridDim.x * blockIdx.y;
  const int sid = (bid & 7) * 64 + (bid >> 3);
  const int bx = sid & 15;
  const int bh = sid >> 4;                   // b*16+h

  const int t = threadIdx.x;
  const int lane = t & 63;
  const int wv = t >> 6;
  const int lg = lane >> 4, lr = lane & 15;
  const int q0 = bx * 128 + wv * 32;

  const u16* Qp = qb + (size_t)bh * 2048 * 64;
  const u16* Kp = kb + (size_t)bh * 2048 * 64;
  const u16* Vt = vtb + (size_t)bh * 64 * 2048;
  char* Pw = (char*)&Pl[wv][0];
  const int swz = (lr & 7) << 4;             // P-tile XOR swizzle only (round-5 proven)

  // stage tile into buffer: LINEAR layout, chunk c -> LDS element c*8 (same as gemm_bt).
  auto stage = [&](int tile, int buf) {
    int j0 = tile * 64;
    for (int i = 0; i < 2; ++i) {
      int cbase = wv * 128 + i * 64;         // wave-uniform chunk base
      int c = cbase + lane;                  // this lane's chunk (0..511)
      int row = c >> 3;
      int col = (c & 7) * 8;
      gload_lds16(Kp + (size_t)(j0 + row) * 64 + col, &Kb[buf][cbase * 8]);
      gload_lds16(Vt + (size_t)row * 2048 + j0 + col, &Vb[buf][cbase * 8]);
    }
  };

  // Q fragments: qf[qi][h] = Q[q0+qi*16+lr][h*32 + lg*8 ..+7]
  bf16x8 qf[2][2];
  for (int qi = 0; qi < 2; ++qi)
    for (int h = 0; h < 2; ++h)
      qf[qi][h] = *reinterpret_cast<const bf16x8*>(&Qp[(size_t)(q0 + qi * 16 + lr) * 64 + h * 32 + lg * 8]);

  f32x4 o[2][4];                             // o[qi][d]: col=q(lr), row=d*16+lg*4+r
  for (int qi = 0; qi < 2; ++qi)
    for (int d = 0; d < 4; ++d) o[qi][d] = (f32x4)0.0f;
  float m[2] = {-1e30f, -1e30f};
  float l[2] = {0.0f, 0.0f};

  stage(0, 0);
  __syncthreads();                            // drains vmcnt: tile 0 ready
  int cur = 0;

  for (int tt = 0; tt < 32; ++tt) {
    if (tt < 31) stage(tt + 1, cur ^ 1);      // prefetch next tile into other buffer
    const int j0 = tt * 64;

    // ---- QK^T (swapped): s[qi][kc] -> lane: q=q0+qi*16+lr, key=j0+kc*16+lg*4+r
    f32x4 s[2][4];
    for (int kc = 0; kc < 4; ++kc) {
      bf16x8 kf0 = *reinterpret_cast<const bf16x8*>(&Kb[cur][(kc * 16 + lr) * 64 + lg * 8]);
      bf16x8 kf1 = *reinterpret_cast<const bf16x8*>(&Kb[cur][(kc * 16 + lr) * 64 + 32 + lg * 8]);
      for (int qi = 0; qi < 2; ++qi) {
        f32x4 z = (f32x4)0.0f;
        z = MFMA16(kf0, qf[qi][0], z, 0, 0, 0);
        z = MFMA16(kf1, qf[qi][1], z, 0, 0, 0);
        s[qi][kc] = z;
      }
    }
    // ---- mask band |i-j| <= 16 (only chunks overlapping this wave's band)
    if (j0 + 63 >= q0 - 16 && j0 <= q0 + 47) {
      for (int qi = 0; qi < 2; ++qi)
        for (int kc = 0; kc < 4; ++kc)
          for (int r = 0; r < 4; ++r) {
            int i = q0 + qi * 16 + lr;
            int j = j0 + kc * 16 + lg * 4 + r;
            int dd = i - j; if (dd < 0) dd = -dd;
            if (dd <= 16) s[qi][kc][r] = -1e38f;
          }
    }
    // ---- chunk row-max (register tree + 2 shuffles)
    float pm[2];
    for (int qi = 0; qi < 2; ++qi) {
      f32x4 t4 = s[qi][0];
      t4 = __builtin_elementwise_max(t4, s[qi][1]);
      t4 = __builtin_elementwise_max(t4, s[qi][2]);
      t4 = __builtin_elementwise_max(t4, s[qi][3]);
      float x = fmaxf(fmaxf(t4[0], t4[1]), fmaxf(t4[2], t4[3]));
      x = fmaxf(x, __shfl_xor(x, 16));
      x = fmaxf(x, __shfl_xor(x, 32));
      pm[qi] = x;
    }
    // ---- defer-max: rescale only when max grew past threshold
    bool need = (pm[0] > m[0] + 8.0f) || (pm[1] > m[1] + 8.0f);
    if (__any((int)need)) {
      for (int qi = 0; qi < 2; ++qi) {
        float mn = fmaxf(m[qi], pm[qi]);
        float a = __expf(m[qi] - mn);
        m[qi] = mn;
        l[qi] *= a;
        for (int d = 0; d < 4; ++d) o[qi][d] *= a;
      }
    }
    // ---- p = exp(s-m), pack to LDS, accumulate l
    for (int qi = 0; qi < 2; ++qi) {
      float sum = 0.0f;
      int rowbase = (qi * 16 + lr) * 128;
      for (int kc = 0; kc < 4; ++kc) {
        float p0 = __expf(s[qi][kc][0] - m[qi]);
        float p1 = __expf(s[qi][kc][1] - m[qi]);
        float p2 = __expf(s[qi][kc][2] - m[qi]);
        float p3 = __expf(s[qi][kc][3] - m[qi]);
        sum += (p0 + p1) + (p2 + p3);
        uint2 pk;
        pk.x = cvt_pk_bf16(p0, p1);
        pk.y = cvt_pk_bf16(p2, p3);
        *reinterpret_cast<uint2*>(Pw + ((rowbase + kc * 32 + lg * 8) ^ swz)) = pk;
      }
      sum += __shfl_xor(sum, 16);
      sum += __shfl_xor(sum, 32);
      l[qi] += sum;
    }
    asm volatile("s_waitcnt lgkmcnt(0)" ::: "memory");
    // ---- PV (swapped): o[qi][d] += mfma(Vfrag, Pfrag)
    for (int kh = 0; kh < 2; ++kh) {
      bf16x8 pa[2];
      for (int qi = 0; qi < 2; ++qi)
        pa[qi] = *reinterpret_cast<const bf16x8*>(
            Pw + (((qi * 16 + lr) * 128 + kh * 64 + lg * 16) ^ swz));
      for (int d = 0; d < 4; ++d) {
        bf16x8 vf = *reinterpret_cast<const bf16x8*>(
            &Vb[cur][(d * 16 + lr) * 64 + kh * 32 + lg * 8]);
        for (int qi = 0; qi < 2; ++qi)
          o[qi][d] = MFMA16(vf, pa[qi], o[qi][d], 0, 0, 0);
      }
    }
    __syncthreads();                          // staging of tt+1 drained; reads of tt done
    cur ^= 1;
  }

  // ---- epilogue: normalize and write [B,T,C] bf16
  int b = bh >> 4, h = bh & 15;
  for (int qi = 0; qi < 2; ++qi) {
    float inv = 1.0f / l[qi];
    size_t rowoff = ((size_t)b * 2048 + q0 + qi * 16 + lr) * 1024 + h * 64;
    for (int d = 0; d < 4; ++d) {
      uint2 pk;
      pk.x = cvt_pk_bf16(o[qi][d][0] * inv, o[qi][d][1] * inv);
      pk.y = cvt_pk_bf16(o[qi][d][2] * inv, o[qi][d][3] * inv);
      *reinterpret_cast<uint2*>(&ab[rowoff + d * 16 + lg * 4]) = pk;
    }
  }
}

// ---------------- launcher ----------------
extern "C" void kernel_launch(void* const* d_in, const int* in_sizes, int n_in,
                              void* d_out, int out_size, void* d_ws, size_t ws_size,
                              hipStream_t stream) {
  const float* x  = (const float*)d_in[0];
  const float* Wq = (const float*)d_in[1];
  const float* bq = (const float*)d_in[2];
  const float* Wk = (const float*)d_in[3];
  const float* bk = (const float*)d_in[4];
  const float* Wv = (const float*)d_in[5];
  const float* bv = (const float*)d_in[6];
  const float* Wo = (const float*)d_in[7];
  const float* bo = (const float*)d_in[8];

  u16* ws  = (u16*)d_ws;
  u16* xb  = ws;                 // 4096*1024 bf16 (reused for attention output)
  u16* wqb = ws + 4194304;
  u16* wkb = ws + 5242880;
  u16* wvb = ws + 6291456;
  u16* wob = ws + 7340032;
  u16* qbf = ws + 8388608;
  u16* kbf = ws + 12582912;
  u16* vbf = ws + 16777216;
  u16* ab  = xb;

  // fp32 -> bf16
  f2b_kernel<<<4096, 256, 0, stream>>>(x, xb, 1048576);
  f2b4_kernel<<<dim3(1024, 4), 256, 0, stream>>>(Wq, Wk, Wv, Wo, wqb, wkb, wvb, wob, 262144);

  dim3 gg(32, 8);
  gemm_bt<0><<<gg, 256, 0, stream>>>(xb, wqb, bq, qbf, 0.125f);  // Q (scaled)
  gemm_bt<0><<<gg, 256, 0, stream>>>(xb, wkb, bk, kbf, 1.0f);    // K
  gemm_bt<1><<<gg, 256, 0, stream>>>(xb, wvb, bv, vbf, 1.0f);    // V^T

  attn_kernel<<<dim3(16, 32), 256, 0, stream>>>(qbf, kbf, vbf, ab);

  gemm_bt<2><<<gg, 256, 0, stream>>>(ab, wob, bo, d_out, 1.0f);  // out proj (fp32)
}

// Round 9
// 177.092 us; speedup vs baseline: 1.9421x; 1.0092x over previous
//
#include <hip/hip_runtime.h>
#include <stdint.h>

// LocalAttention: x[2,2048,1024] -> QKV proj -> anti-local attention (keep |i-j|>16) -> out proj.
// Round 9: fused QKV GEMM (one 768-block launch, bm-grouped XCD remap) replacing three
// 256-block launches. Attention kernel unchanged from round 8 (proven: 78us).

typedef unsigned short u16;
typedef short bf16x8 __attribute__((ext_vector_type(8)));
typedef float f32x4 __attribute__((ext_vector_type(4)));

#define MFMA16 __builtin_amdgcn_mfma_f32_16x16x32_bf16

__device__ __forceinline__ u16 f2bf(float f) {
  union { float f; uint32_t u; } v; v.f = f;
  return (u16)((v.u + 0x7fffu + ((v.u >> 16) & 1u)) >> 16);
}

__device__ __forceinline__ uint32_t cvt_pk_bf16(float lo, float hi) {
  uint32_t d;
  asm("v_cvt_pk_bf16_f32 %0, %1, %2" : "=v"(d) : "v"(lo), "v"(hi));
  return d;
}

__device__ __forceinline__ void gload_lds16(const void* g, void* l) {
  __builtin_amdgcn_global_load_lds(
      (const __attribute__((address_space(1))) unsigned int*)g,
      (__attribute__((address_space(3))) unsigned int*)l, 16, 0, 0);
}

// ---------------- fp32 -> bf16 conversion ----------------
__global__ void f2b_kernel(const float* __restrict__ in, u16* __restrict__ out, int n4) {
  int i = blockIdx.x * blockDim.x + threadIdx.x;
  if (i < n4) {
    float4 v = reinterpret_cast<const float4*>(in)[i];
    ushort4 o;
    o.x = f2bf(v.x); o.y = f2bf(v.y); o.z = f2bf(v.z); o.w = f2bf(v.w);
    reinterpret_cast<ushort4*>(out)[i] = o;
  }
}

// all four weight matrices in one launch (grid.y selects)
__global__ void f2b4_kernel(const float* __restrict__ a, const float* __restrict__ b,
                            const float* __restrict__ c, const float* __restrict__ d,
                            u16* __restrict__ oa, u16* __restrict__ ob,
                            u16* __restrict__ oc, u16* __restrict__ od, int n4) {
  int i = blockIdx.x * blockDim.x + threadIdx.x;
  if (i >= n4) return;
  int w = blockIdx.y;
  const float* src = (w == 0) ? a : (w == 1) ? b : (w == 2) ? c : d;
  u16* dst = (w == 0) ? oa : (w == 1) ? ob : (w == 2) ? oc : od;
  float4 v = reinterpret_cast<const float4*>(src)[i];
  ushort4 o;
  o.x = f2bf(v.x); o.y = f2bf(v.y); o.z = f2bf(v.z); o.w = f2bf(v.w);
  reinterpret_cast<ushort4*>(dst)[i] = o;
}

// ---------------- fused QKV GEMM ----------------
// C_sel[M=4096,N=1024] = A @ W_sel^T + b_sel for sel in {Q,K,V}; 768 blocks.
// sid (bm-grouped, XCD-remapped): bm = sid/24, jy = sid%24; sel = jy>>3, bn0 = (jy&7)*128.
// Q -> [B,H,T,D] scaled 1/8; K -> [B,H,T,D]; V -> [B,H,D,T] (transposed).
__global__ __launch_bounds__(256) void gemm_qkv(
    const u16* __restrict__ A,
    const u16* __restrict__ Wqb, const u16* __restrict__ Wkb, const u16* __restrict__ Wvb,
    const float* __restrict__ bqp, const float* __restrict__ bkp, const float* __restrict__ bvp,
    u16* __restrict__ qo, u16* __restrict__ ko, u16* __restrict__ vo)
{
  constexpr int K = 1024;
  __shared__ __align__(16) u16 As[128 * 64];
  __shared__ __align__(16) u16 Bs[128 * 64];

  // XCD remap: 768 = 8 XCDs x 96; XCD k gets sids k*96.. (= bm 4k..4k+3, all 24 jy each)
  const int bid = blockIdx.x + gridDim.x * blockIdx.y;
  const int sid = (bid & 7) * 96 + (bid >> 3);
  const int bm0 = (sid / 24) * 128;
  const int jy = sid % 24;
  const int sel = jy >> 3;
  const int bn0 = (jy & 7) * 128;

  const u16* Bw = (sel == 0) ? Wqb : (sel == 1) ? Wkb : Wvb;
  const float* bias = (sel == 0) ? bqp : (sel == 1) ? bkp : bvp;
  const float scale = (sel == 0) ? 0.125f : 1.0f;

  const int t = threadIdx.x;
  const int lane = t & 63;
  const int wv = t >> 6;
  const int wm = (wv >> 1) * 64;
  const int wn = (wv & 1) * 64;
  const int lg = lane >> 4;   // 0..3
  const int lr = lane & 15;   // 0..15

  f32x4 acc[4][4];
  for (int i = 0; i < 4; ++i)
    for (int j = 0; j < 4; ++j) acc[i][j] = (f32x4)0.0f;

  for (int k0 = 0; k0 < K; k0 += 64) {
    for (int it = 0; it < 4; ++it) {
      int chunk = it * 256 + t;
      int row = chunk >> 3;
      int col = (chunk & 7) * 8;
      int base = (it * 256 + wv * 64) * 8;
      gload_lds16(A  + (size_t)(bm0 + row) * K + k0 + col, &As[base]);
      gload_lds16(Bw + (size_t)(bn0 + row) * K + k0 + col, &Bs[base]);
    }
    __syncthreads();
    for (int kk = 0; kk < 2; ++kk) {
      bf16x8 af[4], bfr[4];
      for (int i = 0; i < 4; ++i)
        af[i] = *reinterpret_cast<const bf16x8*>(&As[(wm + i * 16 + lr) * 64 + kk * 32 + lg * 8]);
      for (int j = 0; j < 4; ++j)
        bfr[j] = *reinterpret_cast<const bf16x8*>(&Bs[(wn + j * 16 + lr) * 64 + kk * 32 + lg * 8]);
      for (int i = 0; i < 4; ++i)
        for (int j = 0; j < 4; ++j)
          acc[i][j] = MFMA16(af[i], bfr[j], acc[i][j], 0, 0, 0);
    }
    __syncthreads();
  }

  for (int j = 0; j < 4; ++j) {
    int gn = bn0 + wn + j * 16 + lr;
    float bv = bias[gn];
    for (int i = 0; i < 4; ++i) {
      for (int r = 0; r < 4; ++r) {
        int gm = bm0 + wm + i * 16 + lg * 4 + r;
        float val = (acc[i][j][r] + bv) * scale;
        int b = gm >> 11, tt = gm & 2047;
        int h = gn >> 6,  d = gn & 63;
        u16 o = f2bf(val);
        if (sel == 0)
          qo[((size_t)(b * 16 + h) * 2048 + tt) * 64 + d] = o;
        else if (sel == 1)
          ko[((size_t)(b * 16 + h) * 2048 + tt) * 64 + d] = o;
        else
          vo[((size_t)(b * 16 + h) * 64 + d) * 2048 + tt] = o;
      }
    }
  }
}

// ---------------- out-proj GEMM: C[M,N] fp32 = A @ W^T + bias ----------------
__global__ __launch_bounds__(256) void gemm_out(
    const u16* __restrict__ A, const u16* __restrict__ Bw,
    const float* __restrict__ bias, float* __restrict__ outp)
{
  constexpr int K = 1024;
  __shared__ __align__(16) u16 As[128 * 64];
  __shared__ __align__(16) u16 Bs[128 * 64];
  const int t = threadIdx.x;
  const int lane = t & 63;
  const int wv = t >> 6;
  const int bm0 = blockIdx.x * 128;
  const int bn0 = blockIdx.y * 128;
  const int wm = (wv >> 1) * 64;
  const int wn = (wv & 1) * 64;
  const int lg = lane >> 4;
  const int lr = lane & 15;

  f32x4 acc[4][4];
  for (int i = 0; i < 4; ++i)
    for (int j = 0; j < 4; ++j) acc[i][j] = (f32x4)0.0f;

  for (int k0 = 0; k0 < K; k0 += 64) {
    for (int it = 0; it < 4; ++it) {
      int chunk = it * 256 + t;
      int row = chunk >> 3;
      int col = (chunk & 7) * 8;
      int base = (it * 256 + wv * 64) * 8;
      gload_lds16(A  + (size_t)(bm0 + row) * K + k0 + col, &As[base]);
      gload_lds16(Bw + (size_t)(bn0 + row) * K + k0 + col, &Bs[base]);
    }
    __syncthreads();
    for (int kk = 0; kk < 2; ++kk) {
      bf16x8 af[4], bfr[4];
      for (int i = 0; i < 4; ++i)
        af[i] = *reinterpret_cast<const bf16x8*>(&As[(wm + i * 16 + lr) * 64 + kk * 32 + lg * 8]);
      for (int j = 0; j < 4; ++j)
        bfr[j] = *reinterpret_cast<const bf16x8*>(&Bs[(wn + j * 16 + lr) * 64 + kk * 32 + lg * 8]);
      for (int i = 0; i < 4; ++i)
        for (int j = 0; j < 4; ++j)
          acc[i][j] = MFMA16(af[i], bfr[j], acc[i][j], 0, 0, 0);
    }
    __syncthreads();
  }

  for (int j = 0; j < 4; ++j) {
    int gn = bn0 + wn + j * 16 + lr;
    float bv = bias[gn];
    for (int i = 0; i < 4; ++i)
      for (int r = 0; r < 4; ++r) {
        int gm = bm0 + wm + i * 16 + lg * 4 + r;
        outp[(size_t)gm * 1024 + gn] = acc[i][j][r] + bv;
      }
  }
}

// ---------------- attention (round-8 proven: linear LDS K/V dbuf + XCD remap) ----------------
__global__ __launch_bounds__(256, 2) void attn_kernel(
    const u16* __restrict__ qb, const u16* __restrict__ kb,
    const u16* __restrict__ vtb, u16* __restrict__ ab)
{
  __shared__ __align__(16) u16 Kb[2][64 * 64];
  __shared__ __align__(16) u16 Vb[2][64 * 64];
  __shared__ __align__(16) u16 Pl[4][32 * 64];

  // XCD-aware remap: 512 = 8 XCDs x 64; XCD k serves heads 4k..4k+3 (2MB K/V -> L2-fits)
  const int bid = blockIdx.x + gridDim.x * blockIdx.y;
  const int sid = (bid & 7) * 64 + (bid >> 3);
  const int bx = sid & 15;
  const int bh = sid >> 4;                   // b*16+h

  const int t = threadIdx.x;
  const int lane = t & 63;
  const int wv = t >> 6;
  const int lg = lane >> 4, lr = lane & 15;
  const int q0 = bx * 128 + wv * 32;

  const u16* Qp = qb + (size_t)bh * 2048 * 64;
  const u16* Kp = kb + (size_t)bh * 2048 * 64;
  const u16* Vt = vtb + (size_t)bh * 64 * 2048;
  char* Pw = (char*)&Pl[wv][0];
  const int swz = (lr & 7) << 4;             // P-tile XOR swizzle only (round-5 proven)

  auto stage = [&](int tile, int buf) {
    int j0 = tile * 64;
    for (int i = 0; i < 2; ++i) {
      int cbase = wv * 128 + i * 64;
      int c = cbase + lane;
      int row = c >> 3;
      int col = (c & 7) * 8;
      gload_lds16(Kp + (size_t)(j0 + row) * 64 + col, &Kb[buf][cbase * 8]);
      gload_lds16(Vt + (size_t)row * 2048 + j0 + col, &Vb[buf][cbase * 8]);
    }
  };

  bf16x8 qf[2][2];
  for (int qi = 0; qi < 2; ++qi)
    for (int h = 0; h < 2; ++h)
      qf[qi][h] = *reinterpret_cast<const bf16x8*>(&Qp[(size_t)(q0 + qi * 16 + lr) * 64 + h * 32 + lg * 8]);

  f32x4 o[2][4];
  for (int qi = 0; qi < 2; ++qi)
    for (int d = 0; d < 4; ++d) o[qi][d] = (f32x4)0.0f;
  float m[2] = {-1e30f, -1e30f};
  float l[2] = {0.0f, 0.0f};

  stage(0, 0);
  __syncthreads();
  int cur = 0;

  for (int tt = 0; tt < 32; ++tt) {
    if (tt < 31) stage(tt + 1, cur ^ 1);
    const int j0 = tt * 64;

    f32x4 s[2][4];
    for (int kc = 0; kc < 4; ++kc) {
      bf16x8 kf0 = *reinterpret_cast<const bf16x8*>(&Kb[cur][(kc * 16 + lr) * 64 + lg * 8]);
      bf16x8 kf1 = *reinterpret_cast<const bf16x8*>(&Kb[cur][(kc * 16 + lr) * 64 + 32 + lg * 8]);
      for (int qi = 0; qi < 2; ++qi) {
        f32x4 z = (f32x4)0.0f;
        z = MFMA16(kf0, qf[qi][0], z, 0, 0, 0);
        z = MFMA16(kf1, qf[qi][1], z, 0, 0, 0);
        s[qi][kc] = z;
      }
    }
    if (j0 + 63 >= q0 - 16 && j0 <= q0 + 47) {
      for (int qi = 0; qi < 2; ++qi)
        for (int kc = 0; kc < 4; ++kc)
          for (int r = 0; r < 4; ++r) {
            int i = q0 + qi * 16 + lr;
            int j = j0 + kc * 16 + lg * 4 + r;
            int dd = i - j; if (dd < 0) dd = -dd;
            if (dd <= 16) s[qi][kc][r] = -1e38f;
          }
    }
    float pm[2];
    for (int qi = 0; qi < 2; ++qi) {
      f32x4 t4 = s[qi][0];
      t4 = __builtin_elementwise_max(t4, s[qi][1]);
      t4 = __builtin_elementwise_max(t4, s[qi][2]);
      t4 = __builtin_elementwise_max(t4, s[qi][3]);
      float x = fmaxf(fmaxf(t4[0], t4[1]), fmaxf(t4[2], t4[3]));
      x = fmaxf(x, __shfl_xor(x, 16));
      x = fmaxf(x, __shfl_xor(x, 32));
      pm[qi] = x;
    }
    bool need = (pm[0] > m[0] + 8.0f) || (pm[1] > m[1] + 8.0f);
    if (__any((int)need)) {
      for (int qi = 0; qi < 2; ++qi) {
        float mn = fmaxf(m[qi], pm[qi]);
        float a = __expf(m[qi] - mn);
        m[qi] = mn;
        l[qi] *= a;
        for (int d = 0; d < 4; ++d) o[qi][d] *= a;
      }
    }
    for (int qi = 0; qi < 2; ++qi) {
      float sum = 0.0f;
      int rowbase = (qi * 16 + lr) * 128;
      for (int kc = 0; kc < 4; ++kc) {
        float p0 = __expf(s[qi][kc][0] - m[qi]);
        float p1 = __expf(s[qi][kc][1] - m[qi]);
        float p2 = __expf(s[qi][kc][2] - m[qi]);
        float p3 = __expf(s[qi][kc][3] - m[qi]);
        sum += (p0 + p1) + (p2 + p3);
        uint2 pk;
        pk.x = cvt_pk_bf16(p0, p1);
        pk.y = cvt_pk_bf16(p2, p3);
        *reinterpret_cast<uint2*>(Pw + ((rowbase + kc * 32 + lg * 8) ^ swz)) = pk;
      }
      sum += __shfl_xor(sum, 16);
      sum += __shfl_xor(sum, 32);
      l[qi] += sum;
    }
    asm volatile("s_waitcnt lgkmcnt(0)" ::: "memory");
    for (int kh = 0; kh < 2; ++kh) {
      bf16x8 pa[2];
      for (int qi = 0; qi < 2; ++qi)
        pa[qi] = *reinterpret_cast<const bf16x8*>(
            Pw + (((qi * 16 + lr) * 128 + kh * 64 + lg * 16) ^ swz));
      for (int d = 0; d < 4; ++d) {
        bf16x8 vf = *reinterpret_cast<const bf16x8*>(
            &Vb[cur][(d * 16 + lr) * 64 + kh * 32 + lg * 8]);
        for (int qi = 0; qi < 2; ++qi)
          o[qi][d] = MFMA16(vf, pa[qi], o[qi][d], 0, 0, 0);
      }
    }
    __syncthreads();
    cur ^= 1;
  }

  int b = bh >> 4, h = bh & 15;
  for (int qi = 0; qi < 2; ++qi) {
    float inv = 1.0f / l[qi];
    size_t rowoff = ((size_t)b * 2048 + q0 + qi * 16 + lr) * 1024 + h * 64;
    for (int d = 0; d < 4; ++d) {
      uint2 pk;
      pk.x = cvt_pk_bf16(o[qi][d][0] * inv, o[qi][d][1] * inv);
      pk.y = cvt_pk_bf16(o[qi][d][2] * inv, o[qi][d][3] * inv);
      *reinterpret_cast<uint2*>(&ab[rowoff + d * 16 + lg * 4]) = pk;
    }
  }
}

// ---------------- launcher ----------------
extern "C" void kernel_launch(void* const* d_in, const int* in_sizes, int n_in,
                              void* d_out, int out_size, void* d_ws, size_t ws_size,
                              hipStream_t stream) {
  const float* x  = (const float*)d_in[0];
  const float* Wq = (const float*)d_in[1];
  const float* bq = (const float*)d_in[2];
  const float* Wk = (const float*)d_in[3];
  const float* bk = (const float*)d_in[4];
  const float* Wv = (const float*)d_in[5];
  const float* bv = (const float*)d_in[6];
  const float* Wo = (const float*)d_in[7];
  const float* bo = (const float*)d_in[8];

  u16* ws  = (u16*)d_ws;
  u16* xb  = ws;                 // 4096*1024 bf16 (reused for attention output)
  u16* wqb = ws + 4194304;
  u16* wkb = ws + 5242880;
  u16* wvb = ws + 6291456;
  u16* wob = ws + 7340032;
  u16* qbf = ws + 8388608;
  u16* kbf = ws + 12582912;
  u16* vbf = ws + 16777216;
  u16* ab  = xb;

  // fp32 -> bf16
  f2b_kernel<<<4096, 256, 0, stream>>>(x, xb, 1048576);
  f2b4_kernel<<<dim3(1024, 4), 256, 0, stream>>>(Wq, Wk, Wv, Wo, wqb, wkb, wvb, wob, 262144);

  // fused QKV projection (Q scaled 1/8, V transposed)
  gemm_qkv<<<dim3(32, 24), 256, 0, stream>>>(xb, wqb, wkb, wvb, bq, bk, bv, qbf, kbf, vbf);

  attn_kernel<<<dim3(16, 32), 256, 0, stream>>>(qbf, kbf, vbf, ab);

  gemm_out<<<dim3(32, 8), 256, 0, stream>>>(ab, wob, bo, (float*)d_out);
}

// Round 10
// 167.140 us; speedup vs baseline: 2.0578x; 1.0595x over previous
//
#include <hip/hip_runtime.h>
#include <stdint.h>

// LocalAttention: x[2,2048,1024] -> QKV proj -> anti-local attention (keep |i-j|>16) -> out proj.
// Round 10: attn K/V LDS rows padded 64->72 u16 (144B) for conflict-free ds_read_b128/ds_write_b128;
// staging via registers + padded linear ds_write (NO XOR on K/V anywhere). P-tile XOR kept (proven).
// Fused QKV GEMM + out-proj + f2b unchanged from round 9.

typedef unsigned short u16;
typedef short bf16x8 __attribute__((ext_vector_type(8)));
typedef float f32x4 __attribute__((ext_vector_type(4)));

#define MFMA16 __builtin_amdgcn_mfma_f32_16x16x32_bf16

__device__ __forceinline__ u16 f2bf(float f) {
  union { float f; uint32_t u; } v; v.f = f;
  return (u16)((v.u + 0x7fffu + ((v.u >> 16) & 1u)) >> 16);
}

__device__ __forceinline__ uint32_t cvt_pk_bf16(float lo, float hi) {
  uint32_t d;
  asm("v_cvt_pk_bf16_f32 %0, %1, %2" : "=v"(d) : "v"(lo), "v"(hi));
  return d;
}

__device__ __forceinline__ void gload_lds16(const void* g, void* l) {
  __builtin_amdgcn_global_load_lds(
      (const __attribute__((address_space(1))) unsigned int*)g,
      (__attribute__((address_space(3))) unsigned int*)l, 16, 0, 0);
}

// ---------------- fp32 -> bf16 conversion ----------------
__global__ void f2b_kernel(const float* __restrict__ in, u16* __restrict__ out, int n4) {
  int i = blockIdx.x * blockDim.x + threadIdx.x;
  if (i < n4) {
    float4 v = reinterpret_cast<const float4*>(in)[i];
    ushort4 o;
    o.x = f2bf(v.x); o.y = f2bf(v.y); o.z = f2bf(v.z); o.w = f2bf(v.w);
    reinterpret_cast<ushort4*>(out)[i] = o;
  }
}

// all four weight matrices in one launch (grid.y selects)
__global__ void f2b4_kernel(const float* __restrict__ a, const float* __restrict__ b,
                            const float* __restrict__ c, const float* __restrict__ d,
                            u16* __restrict__ oa, u16* __restrict__ ob,
                            u16* __restrict__ oc, u16* __restrict__ od, int n4) {
  int i = blockIdx.x * blockDim.x + threadIdx.x;
  if (i >= n4) return;
  int w = blockIdx.y;
  const float* src = (w == 0) ? a : (w == 1) ? b : (w == 2) ? c : d;
  u16* dst = (w == 0) ? oa : (w == 1) ? ob : (w == 2) ? oc : od;
  float4 v = reinterpret_cast<const float4*>(src)[i];
  ushort4 o;
  o.x = f2bf(v.x); o.y = f2bf(v.y); o.z = f2bf(v.z); o.w = f2bf(v.w);
  reinterpret_cast<ushort4*>(dst)[i] = o;
}

// ---------------- fused QKV GEMM ----------------
__global__ __launch_bounds__(256) void gemm_qkv(
    const u16* __restrict__ A,
    const u16* __restrict__ Wqb, const u16* __restrict__ Wkb, const u16* __restrict__ Wvb,
    const float* __restrict__ bqp, const float* __restrict__ bkp, const float* __restrict__ bvp,
    u16* __restrict__ qo, u16* __restrict__ ko, u16* __restrict__ vo)
{
  constexpr int K = 1024;
  __shared__ __align__(16) u16 As[128 * 64];
  __shared__ __align__(16) u16 Bs[128 * 64];

  const int bid = blockIdx.x + gridDim.x * blockIdx.y;
  const int sid = (bid & 7) * 96 + (bid >> 3);
  const int bm0 = (sid / 24) * 128;
  const int jy = sid % 24;
  const int sel = jy >> 3;
  const int bn0 = (jy & 7) * 128;

  const u16* Bw = (sel == 0) ? Wqb : (sel == 1) ? Wkb : Wvb;
  const float* bias = (sel == 0) ? bqp : (sel == 1) ? bkp : bvp;
  const float scale = (sel == 0) ? 0.125f : 1.0f;

  const int t = threadIdx.x;
  const int lane = t & 63;
  const int wv = t >> 6;
  const int wm = (wv >> 1) * 64;
  const int wn = (wv & 1) * 64;
  const int lg = lane >> 4;
  const int lr = lane & 15;

  f32x4 acc[4][4];
  for (int i = 0; i < 4; ++i)
    for (int j = 0; j < 4; ++j) acc[i][j] = (f32x4)0.0f;

  for (int k0 = 0; k0 < K; k0 += 64) {
    for (int it = 0; it < 4; ++it) {
      int chunk = it * 256 + t;
      int row = chunk >> 3;
      int col = (chunk & 7) * 8;
      int base = (it * 256 + wv * 64) * 8;
      gload_lds16(A  + (size_t)(bm0 + row) * K + k0 + col, &As[base]);
      gload_lds16(Bw + (size_t)(bn0 + row) * K + k0 + col, &Bs[base]);
    }
    __syncthreads();
    for (int kk = 0; kk < 2; ++kk) {
      bf16x8 af[4], bfr[4];
      for (int i = 0; i < 4; ++i)
        af[i] = *reinterpret_cast<const bf16x8*>(&As[(wm + i * 16 + lr) * 64 + kk * 32 + lg * 8]);
      for (int j = 0; j < 4; ++j)
        bfr[j] = *reinterpret_cast<const bf16x8*>(&Bs[(wn + j * 16 + lr) * 64 + kk * 32 + lg * 8]);
      for (int i = 0; i < 4; ++i)
        for (int j = 0; j < 4; ++j)
          acc[i][j] = MFMA16(af[i], bfr[j], acc[i][j], 0, 0, 0);
    }
    __syncthreads();
  }

  for (int j = 0; j < 4; ++j) {
    int gn = bn0 + wn + j * 16 + lr;
    float bv = bias[gn];
    for (int i = 0; i < 4; ++i) {
      for (int r = 0; r < 4; ++r) {
        int gm = bm0 + wm + i * 16 + lg * 4 + r;
        float val = (acc[i][j][r] + bv) * scale;
        int b = gm >> 11, tt = gm & 2047;
        int h = gn >> 6,  d = gn & 63;
        u16 o = f2bf(val);
        if (sel == 0)
          qo[((size_t)(b * 16 + h) * 2048 + tt) * 64 + d] = o;
        else if (sel == 1)
          ko[((size_t)(b * 16 + h) * 2048 + tt) * 64 + d] = o;
        else
          vo[((size_t)(b * 16 + h) * 64 + d) * 2048 + tt] = o;
      }
    }
  }
}

// ---------------- out-proj GEMM: C[M,N] fp32 = A @ W^T + bias ----------------
__global__ __launch_bounds__(256) void gemm_out(
    const u16* __restrict__ A, const u16* __restrict__ Bw,
    const float* __restrict__ bias, float* __restrict__ outp)
{
  constexpr int K = 1024;
  __shared__ __align__(16) u16 As[128 * 64];
  __shared__ __align__(16) u16 Bs[128 * 64];
  const int t = threadIdx.x;
  const int lane = t & 63;
  const int wv = t >> 6;
  const int bm0 = blockIdx.x * 128;
  const int bn0 = blockIdx.y * 128;
  const int wm = (wv >> 1) * 64;
  const int wn = (wv & 1) * 64;
  const int lg = lane >> 4;
  const int lr = lane & 15;

  f32x4 acc[4][4];
  for (int i = 0; i < 4; ++i)
    for (int j = 0; j < 4; ++j) acc[i][j] = (f32x4)0.0f;

  for (int k0 = 0; k0 < K; k0 += 64) {
    for (int it = 0; it < 4; ++it) {
      int chunk = it * 256 + t;
      int row = chunk >> 3;
      int col = (chunk & 7) * 8;
      int base = (it * 256 + wv * 64) * 8;
      gload_lds16(A  + (size_t)(bm0 + row) * K + k0 + col, &As[base]);
      gload_lds16(Bw + (size_t)(bn0 + row) * K + k0 + col, &Bs[base]);
    }
    __syncthreads();
    for (int kk = 0; kk < 2; ++kk) {
      bf16x8 af[4], bfr[4];
      for (int i = 0; i < 4; ++i)
        af[i] = *reinterpret_cast<const bf16x8*>(&As[(wm + i * 16 + lr) * 64 + kk * 32 + lg * 8]);
      for (int j = 0; j < 4; ++j)
        bfr[j] = *reinterpret_cast<const bf16x8*>(&Bs[(wn + j * 16 + lr) * 64 + kk * 32 + lg * 8]);
      for (int i = 0; i < 4; ++i)
        for (int j = 0; j < 4; ++j)
          acc[i][j] = MFMA16(af[i], bfr[j], acc[i][j], 0, 0, 0);
    }
    __syncthreads();
  }

  for (int j = 0; j < 4; ++j) {
    int gn = bn0 + wn + j * 16 + lr;
    float bv = bias[gn];
    for (int i = 0; i < 4; ++i)
      for (int r = 0; r < 4; ++r) {
        int gm = bm0 + wm + i * 16 + lg * 4 + r;
        outp[(size_t)gm * 1024 + gn] = acc[i][j][r] + bv;
      }
  }
}

// ---------------- attention (padded K/V LDS rows, reg-staged, no K/V XOR) ----------------
// grid 512 blocks remapped XCD-aware. Block: 4 waves, 128 q-rows; wave owns 32 q-rows.
// K tile [64 keys][72 u16], V tile [64 d][72 u16] (only first 64 cols used): 144B row stride
// makes b128 read/write bank = 4*((row%8 + slot)%8) -> all 8 slots, conflict-free.
__global__ __launch_bounds__(256, 2) void attn_kernel(
    const u16* __restrict__ qb, const u16* __restrict__ kb,
    const u16* __restrict__ vtb, u16* __restrict__ ab)
{
  constexpr int KP = 72;                      // padded row stride (u16); 144 B = 9*16 B
  __shared__ __align__(16) u16 Kb[2][64 * KP];
  __shared__ __align__(16) u16 Vb[2][64 * KP];
  __shared__ __align__(16) u16 Pl[4][32 * 64];

  // XCD-aware remap: 512 = 8 XCDs x 64; XCD k serves heads 4k..4k+3 (2MB K/V -> L2-fits)
  const int bid = blockIdx.x + gridDim.x * blockIdx.y;
  const int sid = (bid & 7) * 64 + (bid >> 3);
  const int bx = sid & 15;
  const int bh = sid >> 4;                   // b*16+h

  const int t = threadIdx.x;
  const int lane = t & 63;
  const int wv = t >> 6;
  const int lg = lane >> 4, lr = lane & 15;
  const int q0 = bx * 128 + wv * 32;

  const u16* Qp = qb + (size_t)bh * 2048 * 64;
  const u16* Kp = kb + (size_t)bh * 2048 * 64;
  const u16* Vt = vtb + (size_t)bh * 64 * 2048;
  char* Pw = (char*)&Pl[wv][0];
  const int swz = (lr & 7) << 4;             // P-tile XOR swizzle only (round-5/8 proven)

  // staging geometry: lane owns rows r0, r0+8 (slot sl) for both K and V
  const int sl = lane & 7;
  const int r0 = wv * 16 + (lane >> 3);
  const int sdst0 = r0 * (KP * 2) + sl * 16; // LDS byte dest, padded linear (no XOR)

  uint4 krA, krB, vrA, vrB;                  // in-flight staging registers

#define ISSUE_LOADS(J0N)                                                                 \
  do {                                                                                   \
    krA = *reinterpret_cast<const uint4*>(Kp + (size_t)((J0N) + r0) * 64 + sl * 8);      \
    krB = *reinterpret_cast<const uint4*>(Kp + (size_t)((J0N) + r0 + 8) * 64 + sl * 8);  \
    vrA = *reinterpret_cast<const uint4*>(Vt + (size_t)r0 * 2048 + (J0N) + sl * 8);      \
    vrB = *reinterpret_cast<const uint4*>(Vt + (size_t)(r0 + 8) * 2048 + (J0N) + sl * 8);\
  } while (0)

#define WRITE_LDS(BUF)                                                                   \
  do {                                                                                   \
    *reinterpret_cast<uint4*>((char*)&Kb[BUF][0] + sdst0)                = krA;          \
    *reinterpret_cast<uint4*>((char*)&Kb[BUF][0] + sdst0 + 8 * KP * 2)   = krB;          \
    *reinterpret_cast<uint4*>((char*)&Vb[BUF][0] + sdst0)                = vrA;          \
    *reinterpret_cast<uint4*>((char*)&Vb[BUF][0] + sdst0 + 8 * KP * 2)   = vrB;          \
  } while (0)

  // Q fragments: qf[qi][h] = Q[q0+qi*16+lr][h*32 + lg*8 ..+7]
  bf16x8 qf[2][2];
  for (int qi = 0; qi < 2; ++qi)
    for (int h = 0; h < 2; ++h)
      qf[qi][h] = *reinterpret_cast<const bf16x8*>(&Qp[(size_t)(q0 + qi * 16 + lr) * 64 + h * 32 + lg * 8]);

  f32x4 o[2][4];
  for (int qi = 0; qi < 2; ++qi)
    for (int d = 0; d < 4; ++d) o[qi][d] = (f32x4)0.0f;
  float m[2] = {-1e30f, -1e30f};
  float l[2] = {0.0f, 0.0f};

  ISSUE_LOADS(0);
  WRITE_LDS(0);
  __syncthreads();                            // tile 0 published
  int cur = 0;

  for (int tt = 0; tt < 32; ++tt) {
    if (tt < 31) ISSUE_LOADS((tt + 1) * 64);  // T14: HBM/L2 latency hides under compute
    const int j0 = tt * 64;

    // ---- QK^T (swapped): s[qi][kc] -> lane: q=q0+qi*16+lr, key=j0+kc*16+lg*4+r
    f32x4 s[2][4];
    for (int kc = 0; kc < 4; ++kc) {
      bf16x8 kf0 = *reinterpret_cast<const bf16x8*>(&Kb[cur][(kc * 16 + lr) * KP + lg * 8]);
      bf16x8 kf1 = *reinterpret_cast<const bf16x8*>(&Kb[cur][(kc * 16 + lr) * KP + 32 + lg * 8]);
      for (int qi = 0; qi < 2; ++qi) {
        f32x4 z = (f32x4)0.0f;
        z = MFMA16(kf0, qf[qi][0], z, 0, 0, 0);
        z = MFMA16(kf1, qf[qi][1], z, 0, 0, 0);
        s[qi][kc] = z;
      }
    }
    // ---- mask band |i-j| <= 16
    if (j0 + 63 >= q0 - 16 && j0 <= q0 + 47) {
      for (int qi = 0; qi < 2; ++qi)
        for (int kc = 0; kc < 4; ++kc)
          for (int r = 0; r < 4; ++r) {
            int i = q0 + qi * 16 + lr;
            int j = j0 + kc * 16 + lg * 4 + r;
            int dd = i - j; if (dd < 0) dd = -dd;
            if (dd <= 16) s[qi][kc][r] = -1e38f;
          }
    }
    // ---- chunk row-max
    float pm[2];
    for (int qi = 0; qi < 2; ++qi) {
      f32x4 t4 = s[qi][0];
      t4 = __builtin_elementwise_max(t4, s[qi][1]);
      t4 = __builtin_elementwise_max(t4, s[qi][2]);
      t4 = __builtin_elementwise_max(t4, s[qi][3]);
      float x = fmaxf(fmaxf(t4[0], t4[1]), fmaxf(t4[2], t4[3]));
      x = fmaxf(x, __shfl_xor(x, 16));
      x = fmaxf(x, __shfl_xor(x, 32));
      pm[qi] = x;
    }
    // ---- defer-max rescale
    bool need = (pm[0] > m[0] + 8.0f) || (pm[1] > m[1] + 8.0f);
    if (__any((int)need)) {
      for (int qi = 0; qi < 2; ++qi) {
        float mn = fmaxf(m[qi], pm[qi]);
        float a = __expf(m[qi] - mn);
        m[qi] = mn;
        l[qi] *= a;
        for (int d = 0; d < 4; ++d) o[qi][d] *= a;
      }
    }
    // ---- p = exp(s-m), pack to LDS, accumulate l
    for (int qi = 0; qi < 2; ++qi) {
      float sum = 0.0f;
      int rowbase = (qi * 16 + lr) * 128;
      for (int kc = 0; kc < 4; ++kc) {
        float p0 = __expf(s[qi][kc][0] - m[qi]);
        float p1 = __expf(s[qi][kc][1] - m[qi]);
        float p2 = __expf(s[qi][kc][2] - m[qi]);
        float p3 = __expf(s[qi][kc][3] - m[qi]);
        sum += (p0 + p1) + (p2 + p3);
        uint2 pk;
        pk.x = cvt_pk_bf16(p0, p1);
        pk.y = cvt_pk_bf16(p2, p3);
        *reinterpret_cast<uint2*>(Pw + ((rowbase + kc * 32 + lg * 8) ^ swz)) = pk;
      }
      sum += __shfl_xor(sum, 16);
      sum += __shfl_xor(sum, 32);
      l[qi] += sum;
    }
    asm volatile("s_waitcnt lgkmcnt(0)" ::: "memory");
    // ---- PV (swapped)
    for (int kh = 0; kh < 2; ++kh) {
      bf16x8 pa[2];
      for (int qi = 0; qi < 2; ++qi)
        pa[qi] = *reinterpret_cast<const bf16x8*>(
            Pw + (((qi * 16 + lr) * 128 + kh * 64 + lg * 16) ^ swz));
      for (int d = 0; d < 4; ++d) {
        bf16x8 vf = *reinterpret_cast<const bf16x8*>(
            &Vb[cur][(d * 16 + lr) * KP + kh * 32 + lg * 8]);
        for (int qi = 0; qi < 2; ++qi)
          o[qi][d] = MFMA16(vf, pa[qi], o[qi][d], 0, 0, 0);
      }
    }
    if (tt < 31) WRITE_LDS(cur ^ 1);          // publish next tile (padded linear)
    __syncthreads();
    cur ^= 1;
  }

  // ---- epilogue
  int b = bh >> 4, h = bh & 15;
  for (int qi = 0; qi < 2; ++qi) {
    float inv = 1.0f / l[qi];
    size_t rowoff = ((size_t)b * 2048 + q0 + qi * 16 + lr) * 1024 + h * 64;
    for (int d = 0; d < 4; ++d) {
      uint2 pk;
      pk.x = cvt_pk_bf16(o[qi][d][0] * inv, o[qi][d][1] * inv);
      pk.y = cvt_pk_bf16(o[qi][d][2] * inv, o[qi][d][3] * inv);
      *reinterpret_cast<uint2*>(&ab[rowoff + d * 16 + lg * 4]) = pk;
    }
  }
#undef ISSUE_LOADS
#undef WRITE_LDS
}

// ---------------- launcher ----------------
extern "C" void kernel_launch(void* const* d_in, const int* in_sizes, int n_in,
                              void* d_out, int out_size, void* d_ws, size_t ws_size,
                              hipStream_t stream) {
  const float* x  = (const float*)d_in[0];
  const float* Wq = (const float*)d_in[1];
  const float* bq = (const float*)d_in[2];
  const float* Wk = (const float*)d_in[3];
  const float* bk = (const float*)d_in[4];
  const float* Wv = (const float*)d_in[5];
  const float* bv = (const float*)d_in[6];
  const float* Wo = (const float*)d_in[7];
  const float* bo = (const float*)d_in[8];

  u16* ws  = (u16*)d_ws;
  u16* xb  = ws;                 // 4096*1024 bf16 (reused for attention output)
  u16* wqb = ws + 4194304;
  u16* wkb = ws + 5242880;
  u16* wvb = ws + 6291456;
  u16* wob = ws + 7340032;
  u16* qbf = ws + 8388608;
  u16* kbf = ws + 12582912;
  u16* vbf = ws + 16777216;
  u16* ab  = xb;

  // fp32 -> bf16
  f2b_kernel<<<4096, 256, 0, stream>>>(x, xb, 1048576);
  f2b4_kernel<<<dim3(1024, 4), 256, 0, stream>>>(Wq, Wk, Wv, Wo, wqb, wkb, wvb, wob, 262144);

  // fused QKV projection (Q scaled 1/8, V transposed)
  gemm_qkv<<<dim3(32, 24), 256, 0, stream>>>(xb, wqb, wkb, wvb, bq, bk, bv, qbf, kbf, vbf);

  attn_kernel<<<dim3(16, 32), 256, 0, stream>>>(qbf, kbf, vbf, ab);

  gemm_out<<<dim3(32, 8), 256, 0, stream>>>(ab, wob, bo, (float*)d_out);
}